// Round 9
// baseline (1248.771 us; speedup 1.0000x reference)
//
#include <hip/hip_runtime.h>
#include <math.h>

#define DM 512
#define DSTATE 64
#define HD 64
#define DI 1024
#define NH 16
#define CONVD 1152
#define DIP 2192
#define CHK 128
#define NCH 16
#define BSZ 2
#define SEQL 2048
#define BL (BSZ*SEQL)
#define NLAYER 12
#define EPSF 1e-5f
#define NPAD_IN 2304

typedef __attribute__((ext_vector_type(4))) float f32x4;
typedef __attribute__((ext_vector_type(8))) short s16x8;

__device__ __forceinline__ float bf2f(ushort u) {
    union { unsigned int i; float f; } v; v.i = ((unsigned int)u) << 16; return v.f;
}
__device__ __forceinline__ ushort f2bf(float f) {
    union { float f; unsigned int u; } v; v.f = f;
    unsigned int u = v.u;
    unsigned int r = (u + 0x7fffu + ((u >> 16) & 1u)) >> 16;
    return (ushort)r;
}

#define GLOAD_LDS16(gptr, lptr) __builtin_amdgcn_global_load_lds( \
    (const __attribute__((address_space(1))) void*)(gptr), \
    (__attribute__((address_space(3))) void*)(lptr), 16, 0, 0)

#define MFMA_BF16(a, b, c) __builtin_amdgcn_mfma_f32_16x16x32_bf16(a, b, c, 0, 0, 0)

// ---------------- embed + nerf positional encoding ----------------
__global__ void embed_kernel(const float* __restrict__ x, const float* __restrict__ W,
                             float* __restrict__ h) {
    int tok = blockIdx.x;
    float xe[3];
#pragma unroll
    for (int e = 0; e < 3; e++) {
        float v = x[tok * 3 + e];
        xe[e] = (v == -100.0f) ? 0.0f : v;
    }
    for (int d = threadIdx.x; d < DM; d += blockDim.x) {
        float pe = 0.0f;
        if (d < 510) {
            int e = d / 170, r = d % 170;
            int is_sin = (r < 85);
            int k = is_sin ? r : r - 85;
            float ang = xe[e] * ldexpf(1.0f, k);   // exact in fp32
            double dv = is_sin ? sin((double)ang) : cos((double)ang);
            pe = (float)dv;
        }
        float acc = pe;
#pragma unroll
        for (int e = 0; e < 3; e++) acc += xe[e] * W[e * DM + d];
        h[(size_t)tok * DM + d] = acc;
    }
}

// ---------------- rmsnorm width=512 -> bf16 out ----------------
__global__ __launch_bounds__(256) void rmsnorm512_bf_kernel(const float* __restrict__ in,
                                                            const float* __restrict__ w,
                                                            ushort* __restrict__ out) {
    int tok = blockIdx.x;
    const float* row = in + (size_t)tok * DM;
    float v0 = row[threadIdx.x];
    float v1 = row[threadIdx.x + 256];
    float ss = v0 * v0 + v1 * v1;
    for (int o = 32; o; o >>= 1) ss += __shfl_down(ss, o);
    __shared__ float sbuf[4];
    if ((threadIdx.x & 63) == 0) sbuf[threadIdx.x >> 6] = ss;
    __syncthreads();
    if (threadIdx.x == 0) {
        float s = sbuf[0] + sbuf[1] + sbuf[2] + sbuf[3];
        sbuf[0] = rsqrtf(s / (float)DM + EPSF);
    }
    __syncthreads();
    float rs = sbuf[0];
    ushort* orow = out + (size_t)tok * DM;
    orow[threadIdx.x] = f2bf(v0 * rs * w[threadIdx.x]);
    orow[threadIdx.x + 256] = f2bf(v1 * rs * w[threadIdx.x + 256]);
}

// ---------------- gate silu(z)*y + rmsnorm (width 1024) -> bf16 --------
__global__ __launch_bounds__(256) void gatenorm_kernel(const float* __restrict__ y,
                                                       const ushort* __restrict__ zx,
                                                       const float* __restrict__ gw,
                                                       ushort* __restrict__ yb) {
    int tok = blockIdx.x;
    const ushort* zrow = zx + (size_t)tok * DIP;
    const float* yrow = y + (size_t)tok * DI;
    float v[4];
    float ss = 0.0f;
#pragma unroll
    for (int k = 0; k < 4; k++) {
        int d = threadIdx.x + k * 256;
        float z = bf2f(zrow[d]);
        float s = z / (1.0f + __expf(-z));
        float val = yrow[d] * s;
        v[k] = val;
        ss += val * val;
    }
    for (int o = 32; o; o >>= 1) ss += __shfl_down(ss, o);
    __shared__ float sbuf[4];
    if ((threadIdx.x & 63) == 0) sbuf[threadIdx.x >> 6] = ss;
    __syncthreads();
    if (threadIdx.x == 0) {
        float s = sbuf[0] + sbuf[1] + sbuf[2] + sbuf[3];
        sbuf[0] = rsqrtf(s / (float)DI + EPSF);
    }
    __syncthreads();
    float rs = sbuf[0];
    ushort* ob = yb + (size_t)tok * DI;
#pragma unroll
    for (int k = 0; k < 4; k++) {
        int d = threadIdx.x + k * 256;
        ob[d] = f2bf(v[k] * rs * gw[d]);
    }
}

// ---------------- weight convert+transpose: w[L][K][N] f32 -> wT[L][Npad][K] bf16 ----
__global__ __launch_bounds__(256) void convT_kernel(const float* __restrict__ w,
                                                    ushort* __restrict__ wT,
                                                    int K, int N, int Npad) {
    __shared__ ushort tile[64][65];
    int l = blockIdx.z;
    int n0 = blockIdx.x * 64, k0 = blockIdx.y * 64;
    const float* src = w + (size_t)l * K * N;
    ushort* dst = wT + (size_t)l * Npad * K;
    int tid = threadIdx.x;
#pragma unroll
    for (int t = 0; t < 16; t++) {
        int idx = tid + t * 256;
        int r = idx >> 6, c = idx & 63;
        float v = (n0 + c < N) ? src[(size_t)(k0 + r) * N + n0 + c] : 0.0f;
        tile[c][r] = f2bf(v);
    }
    __syncthreads();
#pragma unroll
    for (int t = 0; t < 16; t++) {
        int idx = tid + t * 256;
        int r = idx >> 6, c = idx & 63;
        dst[(size_t)(n0 + r) * K + k0 + c] = tile[r][c];
    }
}

// ---------------- bf16 MFMA GEMM: C[M,N] = A[M,K] * BT[N,K]^T ----------------
// BM = MT*32 x BN=128 tile, BK=64, 4 waves (2x2), double-buffered prefetch,
// bijective XCD-aware block swizzle (grid must be %8==0).
// MODE 0: bf16 store + dt sidecar; MODE 1: fp32 accumulate; MODE 2: fp32 + bias (head)
template <int MODE, int MT>
__global__ __launch_bounds__(256) void gemm_bf16_kernel(
    const ushort* __restrict__ A, const ushort* __restrict__ BT,
    ushort* __restrict__ Cb, float* __restrict__ Cf, float* __restrict__ aux,
    int N, int Nstride, int K)
{
    __shared__ ushort As[2][MT * 32 * 64];
    __shared__ ushort Bs[2][128 * 64];
    // XCD swizzle: contiguous run of nwg/8 blocks per XCD -> A/B panel L2 reuse
    int nwg = gridDim.x * gridDim.y;
    int w0 = blockIdx.y * gridDim.x + blockIdx.x;
    int wg = (w0 & 7) * (nwg >> 3) + (w0 >> 3);
    int by = wg / gridDim.x, bx = wg - by * gridDim.x;
    int bm = by * (MT * 32), bn = bx * 128;
    int tid = threadIdx.x;
    int lane = tid & 63, wid = tid >> 6;
    int wr = wid >> 1, wc = wid & 1;
    int r15 = lane & 15, q = lane >> 4;
    f32x4 acc[MT][4] = {};
    const int nkt = K >> 6;

#define STAGE_GEMM(b, kt) do {                                              \
        int k0s = (kt) << 6;                                                \
        _Pragma("unroll")                                                   \
        for (int t = 0; t < MT; t++) {                                      \
            int cbase = wid * (MT * 64) + t * 64;                           \
            int chunk = cbase + lane;                                       \
            int row = chunk >> 3, s = chunk & 7;                            \
            int kc = s ^ (row & 7);                                         \
            GLOAD_LDS16(A + (size_t)(bm + row) * K + k0s + kc * 8,          \
                        &As[b][cbase * 8]);                                 \
        }                                                                   \
        _Pragma("unroll")                                                   \
        for (int t = 0; t < 4; t++) {                                       \
            int cbase = wid * 256 + t * 64;                                 \
            int chunk = cbase + lane;                                       \
            int row = chunk >> 3, s = chunk & 7;                            \
            int kc = s ^ (row & 7);                                         \
            GLOAD_LDS16(BT + (size_t)(bn + row) * K + k0s + kc * 8,         \
                        &Bs[b][cbase * 8]);                                 \
        }                                                                   \
    } while (0)

    STAGE_GEMM(0, 0);
    __syncthreads();
    for (int kt = 0; kt < nkt; kt++) {
        int cur = kt & 1;
        if (kt + 1 < nkt) STAGE_GEMM(cur ^ 1, kt + 1);
        const ushort* Ac = As[cur];
        const ushort* Bc = Bs[cur];
#pragma unroll
        for (int kh = 0; kh < 2; kh++) {
            s16x8 av[MT], bv[4];
#pragma unroll
            for (int m = 0; m < MT; m++) {
                int row = wr * (MT * 16) + m * 16 + r15;
                int s = (kh * 4 + q) ^ (row & 7);
                av[m] = *(const s16x8*)(Ac + row * 64 + s * 8);
            }
#pragma unroll
            for (int n = 0; n < 4; n++) {
                int row = wc * 64 + n * 16 + r15;
                int s = (kh * 4 + q) ^ (row & 7);
                bv[n] = *(const s16x8*)(Bc + row * 64 + s * 8);
            }
#pragma unroll
            for (int m = 0; m < MT; m++)
#pragma unroll
                for (int n = 0; n < 4; n++)
                    acc[m][n] = MFMA_BF16(av[m], bv[n], acc[m][n]);
        }
        __syncthreads();   // drains prefetch (vmcnt0) + guards buffer reuse
    }
#undef STAGE_GEMM

#pragma unroll
    for (int m = 0; m < MT; m++) {
        int row0 = bm + wr * (MT * 16) + m * 16 + q * 4;
#pragma unroll
        for (int n = 0; n < 4; n++) {
            int col = bn + wc * 64 + n * 16 + r15;
#pragma unroll
            for (int r = 0; r < 4; r++) {
                float v = acc[m][n][r];
                int rr = row0 + r;
                if (MODE == 0) {
                    if (col < N) {
                        Cb[(size_t)rr * Nstride + col] = f2bf(v);
                        if (col >= DI + CONVD) aux[(size_t)rr * 16 + (col - DI - CONVD)] = v;
                    }
                } else if (MODE == 1) {
                    Cf[(size_t)rr * Nstride + col] += v;
                } else {
                    if (col < N) Cf[(size_t)rr * Nstride + col] = v + aux[col];
                }
            }
        }
    }
}

// ---------------- causal depthwise conv (d=4) + bias + silu ------
__global__ __launch_bounds__(256) void conv_kernel(const ushort* __restrict__ zx,
                                                   const float* __restrict__ cw,
                                                   const float* __restrict__ cb,
                                                   ushort* __restrict__ xc) {
    int gid = blockIdx.x * 256 + threadIdx.x;
    int cu = gid % (CONVD / 8);
    int rb = gid / (CONVD / 8);
    int c8 = cu * 8;
    int l0 = rb * 4;
    int lmod = l0 & (SEQL - 1);

    float wk[4][8];
    const float4* wp = (const float4*)(cw + c8 * 4);
#pragma unroll
    for (int e = 0; e < 8; e++) {
        float4 v = wp[e];
        wk[0][e] = v.x; wk[1][e] = v.y; wk[2][e] = v.z; wk[3][e] = v.w;
    }
    float4 b0 = *(const float4*)(cb + c8);
    float4 b1 = *(const float4*)(cb + c8 + 4);
    float bias[8] = {b0.x, b0.y, b0.z, b0.w, b1.x, b1.y, b1.z, b1.w};

    const ushort* base = zx + (size_t)l0 * DIP + DI + c8;
    s16x8 zero = {};
    s16x8 rows[7];
    rows[0] = (lmod >= 3) ? *(const s16x8*)(base - 3 * DIP) : zero;
    rows[1] = (lmod >= 2) ? *(const s16x8*)(base - 2 * DIP) : zero;
    rows[2] = (lmod >= 1) ? *(const s16x8*)(base - 1 * DIP) : zero;
#pragma unroll
    for (int r = 0; r < 4; r++) rows[3 + r] = *(const s16x8*)(base + (size_t)r * DIP);

    ushort* ob = xc + (size_t)l0 * CONVD + c8;
#pragma unroll
    for (int r = 0; r < 4; r++) {
        s16x8 o;
#pragma unroll
        for (int e = 0; e < 8; e++) {
            float a = bias[e];
#pragma unroll
            for (int k = 0; k < 4; k++)
                a += bf2f((ushort)rows[r + k][e]) * wk[k][e];
            float s = a / (1.0f + __expf(-a));
            o[e] = (short)f2bf(s);
        }
        *(s16x8*)(ob + (size_t)r * CONVD) = o;
    }
}

// ---------------- F1: fused dt-scan + scores + M + y_diag(+D via M-diag) + state ----
// grid (NH, 32 bc); 512 threads (8 waves).
// D*xh folded into M[i,i]; BmT prescaled by ds_j in LDS (state = xh * (ds*Bm)).
__global__ __launch_bounds__(512, 4) void ssd1_kernel(
    const ushort* __restrict__ xc, const float* __restrict__ dtraw,
    const float* __restrict__ dt_bias, const float* __restrict__ A_log,
    const float* __restrict__ Dp, float* __restrict__ acg,
    float* __restrict__ decbuf, float* __restrict__ y, float* __restrict__ S)
{
    __shared__ ushort Mb[128 * 128];
    __shared__ ushort xhT[64 * 136];
    __shared__ ushort BmT[64 * 136];
    __shared__ float sAc[128], sDt[128], sDs[128];
    __shared__ float s_wsum, s_stot;

    int hh = blockIdx.x, bc = blockIdx.y;
    int tid = threadIdx.x, lane = tid & 63, w = tid >> 6;
    int l15 = lane & 15, lq = lane >> 4;
    int bch = bc * NH + hh;
    const size_t xbase = (size_t)(bc * CHK) * CONVD;
    ushort* Cs = Mb;
    ushort* Bs = Mb + 8192;
    float Dh = Dp[hh];

#pragma unroll
    for (int t = 0; t < 2; t++) {
        int cbase = t * 512 + w * 64;
        int chunk = cbase + lane;
        int row = chunk >> 3, s = chunk & 7;
        int kc = s ^ (row & 7);
        GLOAD_LDS16(xc + xbase + (size_t)row * CONVD + DI + DSTATE + kc * 8, Cs + (size_t)cbase * 8);
        GLOAD_LDS16(xc + xbase + (size_t)row * CONVD + DI + kc * 8, Bs + (size_t)cbase * 8);
    }
    {
        int j = tid & 127, pc = tid >> 7;
#pragma unroll
        for (int it = 0; it < 2; it++) {
            int pc8 = pc * 2 + it;
            s16x8 vx = *(const s16x8*)(xc + xbase + (size_t)j * CONVD + hh * HD + pc8 * 8);
            s16x8 vb = *(const s16x8*)(xc + xbase + (size_t)j * CONVD + DI + pc8 * 8);
#pragma unroll
            for (int e = 0; e < 8; e++) {
                int R = pc8 * 8 + e;
                int off = R * 136 + (((j >> 3) ^ (R & 7)) << 3) + (j & 7);
                xhT[off] = (ushort)vx[e];
                BmT[off] = (ushort)vb[e];
            }
        }
    }
    float v_scan = 0.0f, dt_v = 0.0f;
    if (tid < 128) {
        float raw = dtraw[(size_t)(bc * CHK + tid) * 16 + hh] + dt_bias[hh];
        dt_v = raw > 0.0f ? raw + log1pf(__expf(-raw)) : log1pf(__expf(raw));
        v_scan = dt_v * (-__expf(A_log[hh]));
#pragma unroll
        for (int o = 1; o < 64; o <<= 1) {
            float u = __shfl_up(v_scan, o);
            if (lane >= o) v_scan += u;
        }
        if (tid == 63) s_wsum = v_scan;
    }
    __syncthreads();   // B1

    float ac_v = 0.0f;
    if (tid < 128) {
        ac_v = (tid >= 64) ? v_scan + s_wsum : v_scan;
        if (tid == 127) s_stot = ac_v;
    }
    f32x4 acc_s[8] = {};
    {
        int row = w * 16 + l15;
#pragma unroll
        for (int kh = 0; kh < 2; kh++) {
            int sl = (kh * 4 + lq) ^ (row & 7);
            s16x8 av = *(const s16x8*)(Cs + row * 64 + sl * 8);
#pragma unroll
            for (int nj = 0; nj < 8; nj++) {
                int jr = nj * 16 + l15;
                int sl2 = (kh * 4 + lq) ^ (jr & 7);
                s16x8 bv = *(const s16x8*)(Bs + jr * 64 + sl2 * 8);
                acc_s[nj] = MFMA_BF16(av, bv, acc_s[nj]);
            }
        }
    }
    __syncthreads();   // B2

    if (tid < 128) {
        float asum = s_stot;
        sAc[tid] = ac_v;
        sDt[tid] = dt_v;
        sDs[tid] = __expf(asum - ac_v) * dt_v;
        acg[(size_t)bch * CHK + tid] = ac_v;
        if (tid == 0) decbuf[bch] = __expf(asum);
    }
    __syncthreads();   // B3

    // M-build (D folded into diagonal)
#pragma unroll
    for (int nj = 0; nj < 8; nj++) {
        int j = nj * 16 + l15;
        if (nj < w) {
            float acj = sAc[j], dtj = sDt[j];
#pragma unroll
            for (int r = 0; r < 4; r++) {
                int i = w * 16 + lq * 4 + r;
                float v = acc_s[nj][r] * __expf(sAc[i] - acj) * dtj;
                Mb[i * 128 + ((((i & 7) ^ (j >> 3)) << 3) | (j & 7))] = f2bf(v);
            }
        } else if (nj == w) {
            float acj = sAc[j], dtj = sDt[j];
#pragma unroll
            for (int r = 0; r < 4; r++) {
                int i = w * 16 + lq * 4 + r;
                float v;
                if (j < i)       v = acc_s[nj][r] * __expf(sAc[i] - acj) * dtj;
                else if (j == i) v = acc_s[nj][r] * dtj + Dh;   // exp(0)=1; += D*xh via PV
                else             v = 0.0f;
                Mb[i * 128 + ((((i & 7) ^ (j >> 3)) << 3) | (j & 7))] = f2bf(v);
            }
        } else if (nj == w + 1) {
#pragma unroll
            for (int r = 0; r < 4; r++) {
                int i = w * 16 + lq * 4 + r;
                Mb[i * 128 + ((((i & 7) ^ (j >> 3)) << 3) | (j & 7))] = 0;
            }
        }
    }
    // BmT *= ds_j (in place; read only after B4). consecutive-j lanes -> bank-friendly
    {
        int j = tid & 127, g = tid >> 7;
        float dsj = sDs[j];
#pragma unroll
        for (int rr = 0; rr < 16; rr++) {
            int R = g * 16 + rr;
            int off = R * 136 + (((j >> 3) ^ (R & 7)) << 3) + (j & 7);
            BmT[off] = f2bf(bf2f(BmT[off]) * dsj);
        }
    }
    __syncthreads();   // B4

    int ph = w >> 2, iq = w & 3;
    f32x4 acc_y[2][2] = {};
    f32x4 acc_st[2] = {};
    int nn = iq * 16 + l15;
#pragma unroll
    for (int ks = 0; ks < 4; ks++) {
        int cj = ks * 4 + lq;
        s16x8 axh[2];
#pragma unroll
        for (int m = 0; m < 2; m++) {
            int p = ph * 32 + m * 16 + l15;
            axh[m] = *(const s16x8*)(xhT + p * 136 + ((cj ^ (p & 7)) << 3));
        }
        s16x8 bb = *(const s16x8*)(BmT + nn * 136 + ((cj ^ (nn & 7)) << 3));
#pragma unroll
        for (int m = 0; m < 2; m++)
            acc_st[m] = MFMA_BF16(axh[m], bb, acc_st[m]);
        if (ks <= iq) {
            s16x8 bm_[2];
#pragma unroll
            for (int n = 0; n < 2; n++) {
                int i = iq * 32 + n * 16 + l15;
                bm_[n] = *(const s16x8*)(Mb + i * 128 + ((cj ^ (i & 7)) << 3));
            }
#pragma unroll
            for (int m = 0; m < 2; m++)
#pragma unroll
                for (int n = 0; n < 2; n++)
                    acc_y[m][n] = MFMA_BF16(axh[m], bm_[n], acc_y[m][n]);
        }
    }

#pragma unroll
    for (int m = 0; m < 2; m++) {
        int p0 = ph * 32 + m * 16 + lq * 4;
#pragma unroll
        for (int n = 0; n < 2; n++) {
            int i = iq * 32 + n * 16 + l15;
            *(f32x4*)&y[(size_t)(bc * CHK + i) * DI + hh * HD + p0] = acc_y[m][n];
        }
#pragma unroll
        for (int r = 0; r < 4; r++)
            S[(size_t)bch * 4096 + (size_t)(p0 + r) * 64 + nn] = acc_st[m][r];
    }
}

// ---------------- F2: y += exp(ac_i) * (C @ hs^T); hs computed in-block ------
// prefix over chunks c<cc: hs = sum_c S[c] * prod_{k>c} dec[k]  (backward loop)
__global__ __launch_bounds__(256) void ssd2_kernel(
    const ushort* __restrict__ xc, const float* __restrict__ Sg,
    const float* __restrict__ decg, const float* __restrict__ acg,
    float* __restrict__ y)
{
    __shared__ ushort Cs[128 * 64];
    __shared__ ushort Hs[64 * 64];
    __shared__ float sAc[128];
    int hh = blockIdx.x, bc = blockIdx.y;
    int tid = threadIdx.x, lane = tid & 63, wid = tid >> 6;
    int wr = wid >> 1, wc = wid & 1, l15 = lane & 15, lq = lane >> 4;
    int bch = bc * NH + hh;
    int b = bc >> 4, cc = bc & 15;
    const size_t xbase = (size_t)(bc * CHK) * CONVD;
#pragma unroll
    for (int t = 0; t < 4; t++) {
        int cbase = t * 256 + wid * 64;
        int chunk = cbase + lane;
        int row = chunk >> 3, s = chunk & 7;
        int kc = s ^ (row & 7);
        GLOAD_LDS16(xc + xbase + (size_t)row * CONVD + DI + DSTATE + kc * 8, Cs + (size_t)cbase * 8);
    }
    // in-register prefix state (16 f32/thread)
    {
        int p = tid >> 2, n0 = (tid & 3) * 16;
        f32x4 acc4[4] = {};
        float wgt = 1.0f;
        for (int c = cc - 1; c >= 0; --c) {
            int bch_c = (b * NCH + c) * NH + hh;
            const float* src = Sg + (size_t)bch_c * 4096 + p * 64 + n0;
            float dv = decg[bch_c];
#pragma unroll
            for (int q2 = 0; q2 < 4; q2++) {
                f32x4 sv = *(const f32x4*)(src + q2 * 4);
                acc4[q2].x += sv.x * wgt; acc4[q2].y += sv.y * wgt;
                acc4[q2].z += sv.z * wgt; acc4[q2].w += sv.w * wgt;
            }
            wgt *= dv;
        }
#pragma unroll
        for (int g = 0; g < 2; g++) {
            int nch = (n0 >> 3) + g;
            int s = nch ^ (p & 7);
            ushort* dst = Hs + p * 64 + s * 8;
#pragma unroll
            for (int ee = 0; ee < 8; ee++) {
                int idx = g * 8 + ee;
                dst[ee] = f2bf(acc4[idx >> 2][idx & 3]);
            }
        }
    }
    if (tid < 128) sAc[tid] = acg[(size_t)bch * CHK + tid];
    __syncthreads();
    f32x4 acc[2][4] = {};
#pragma unroll
    for (int kh = 0; kh < 2; kh++) {
        s16x8 av[2], bv[4];
#pragma unroll
        for (int m = 0; m < 2; m++) {
            int p = wr * 32 + m * 16 + l15;
            int sl = (kh * 4 + lq) ^ (p & 7);
            av[m] = *(const s16x8*)(Hs + p * 64 + sl * 8);
        }
#pragma unroll
        for (int n = 0; n < 4; n++) {
            int i = wc * 64 + n * 16 + l15;
            int sl = (kh * 4 + lq) ^ (i & 7);
            bv[n] = *(const s16x8*)(Cs + i * 64 + sl * 8);
        }
#pragma unroll
        for (int m = 0; m < 2; m++)
#pragma unroll
            for (int n = 0; n < 4; n++)
                acc[m][n] = MFMA_BF16(av[m], bv[n], acc[m][n]);
    }
#pragma unroll
    for (int m = 0; m < 2; m++) {
        int p0 = wr * 32 + m * 16 + lq * 4;
#pragma unroll
        for (int n = 0; n < 4; n++) {
            int i = wc * 64 + n * 16 + l15;
            float e = __expf(sAc[i]);
            float* dst = &y[(size_t)(bc * CHK + i) * DI + hh * HD + p0];
            f32x4 v = *(f32x4*)dst;
#pragma unroll
            for (int r = 0; r < 4; r++) v[r] += e * acc[m][n][r];
            *(f32x4*)dst = v;
        }
    }
}

extern "C" void kernel_launch(void* const* d_in, const int* in_sizes, int n_in,
                              void* d_out, int out_size, void* d_ws, size_t ws_size,
                              hipStream_t stream) {
    const float* x        = (const float*)d_in[0];
    const float* W_embed  = (const float*)d_in[1];
    const float* rms_w    = (const float*)d_in[2];
    const float* in_w     = (const float*)d_in[3];
    const float* conv_w   = (const float*)d_in[4];
    const float* conv_b   = (const float*)d_in[5];
    const float* dt_bias  = (const float*)d_in[6];
    const float* A_log    = (const float*)d_in[7];
    const float* D_param  = (const float*)d_in[8];
    const float* gnorm_w  = (const float*)d_in[9];
    const float* out_w    = (const float*)d_in[10];
    const float* fnorm_w  = (const float*)d_in[11];
    const float* head_w   = (const float*)d_in[12];
    const float* head_b   = (const float*)d_in[13];
    float* out = (float*)d_out;

    char* p = (char*)d_ws;
    auto alloc = [&](size_t bytes) { char* r = p; p += (bytes + 255) & ~(size_t)255; return r; };

    float*  h_buf   = (float*)alloc((size_t)BL * DM * 4);
    float*  y_buf   = (float*)alloc((size_t)BL * DI * 4);
    float*  S_buf   = (float*)alloc((size_t)BSZ * NCH * NH * HD * DSTATE * 4);
    float*  ac_buf  = (float*)alloc((size_t)BSZ * NCH * NH * CHK * 4);
    float*  dec_buf = (float*)alloc((size_t)BSZ * NCH * NH * 4);
    float*  dtraw   = (float*)alloc((size_t)BL * 16 * 4);
    ushort* xn_bf   = (ushort*)alloc((size_t)BL * DM * 2);
    ushort* zx_bf   = (ushort*)alloc((size_t)BL * DIP * 2);
    ushort* xc_bf   = (ushort*)alloc((size_t)BL * CONVD * 2);
    ushort* y_bf    = (ushort*)alloc((size_t)BL * DI * 2);
    ushort* headT   = (ushort*)alloc((size_t)128 * DM * 2);

    size_t in_full  = (size_t)NLAYER * NPAD_IN * DM * 2;
    size_t out_full = (size_t)NLAYER * DM * DI * 2;
    size_t used = (size_t)(p - (char*)d_ws);
    bool full = (used + in_full + out_full + 4096) <= ws_size;
    ushort* inT  = (ushort*)alloc(full ? in_full  : (size_t)NPAD_IN * DM * 2);
    ushort* outT = (ushort*)alloc(full ? out_full : (size_t)DM * DI * 2);

    embed_kernel<<<BL, 256, 0, stream>>>(x, W_embed, h_buf);
    convT_kernel<<<dim3(2, DM / 64, 1), 256, 0, stream>>>(head_w, headT, DM, 30, 128);
    if (full) {
        convT_kernel<<<dim3(NPAD_IN / 64, DM / 64, NLAYER), 256, 0, stream>>>(
            in_w, inT, DM, DIP, NPAD_IN);
        convT_kernel<<<dim3(DM / 64, DI / 64, NLAYER), 256, 0, stream>>>(
            out_w, outT, DI, DM, DM);
    }

    for (int l = 0; l < NLAYER; l++) {
        const float* rw = rms_w + (size_t)l * DM;
        const float* cw = conv_w + (size_t)l * CONVD * 4;
        const float* cb = conv_b + (size_t)l * CONVD;
        const float* db = dt_bias + (size_t)l * NH;
        const float* al = A_log + (size_t)l * NH;
        const float* dp = D_param + (size_t)l * NH;
        const float* gw = gnorm_w + (size_t)l * DI;

        ushort* inT_l  = full ? inT  + (size_t)l * NPAD_IN * DM : inT;
        ushort* outT_l = full ? outT + (size_t)l * DM * DI      : outT;
        if (!full) {
            convT_kernel<<<dim3(NPAD_IN / 64, DM / 64, 1), 256, 0, stream>>>(
                in_w + (size_t)l * DM * DIP, inT_l, DM, DIP, NPAD_IN);
            convT_kernel<<<dim3(DM / 64, DI / 64, 1), 256, 0, stream>>>(
                out_w + (size_t)l * DI * DM, outT_l, DI, DM, DM);
        }

        rmsnorm512_bf_kernel<<<BL, 256, 0, stream>>>(h_buf, rw, xn_bf);
        gemm_bf16_kernel<0, 2><<<dim3(NPAD_IN / 128, BL / 64), 256, 0, stream>>>(
            xn_bf, inT_l, zx_bf, nullptr, dtraw, DIP, DIP, DM);
        conv_kernel<<<((BL / 4) * (CONVD / 8)) / 256, 256, 0, stream>>>(zx_bf, cw, cb, xc_bf);
        ssd1_kernel<<<dim3(NH, BSZ * NCH), 512, 0, stream>>>(xc_bf, dtraw, db, al, dp,
                                                             ac_buf, dec_buf, y_buf, S_buf);
        ssd2_kernel<<<dim3(NH, BSZ * NCH), 256, 0, stream>>>(xc_bf, S_buf, dec_buf,
                                                             ac_buf, y_buf);
        gatenorm_kernel<<<BL, 256, 0, stream>>>(y_buf, zx_bf, gw, y_bf);
        gemm_bf16_kernel<1, 1><<<dim3(DM / 128, BL / 32), 256, 0, stream>>>(
            y_bf, outT_l, nullptr, h_buf, nullptr, DM, DM, DI);
    }

    rmsnorm512_bf_kernel<<<BL, 256, 0, stream>>>(h_buf, fnorm_w, xn_bf);
    gemm_bf16_kernel<2, 4><<<dim3(1, BL / 128), 256, 0, stream>>>(
        xn_bf, headT, nullptr, out, (float*)head_b, 30, 30, DM);
}

// Round 10
// 1221.645 us; speedup vs baseline: 1.0222x; 1.0222x over previous
//
#include <hip/hip_runtime.h>
#include <math.h>

#define DM 512
#define DSTATE 64
#define HD 64
#define DI 1024
#define NH 16
#define CONVD 1152
#define DIP 2192
#define CHK 128
#define NCH 16
#define BSZ 2
#define SEQL 2048
#define BL (BSZ*SEQL)
#define NLAYER 12
#define EPSF 1e-5f
#define NPAD_IN 2304

typedef __attribute__((ext_vector_type(4))) float f32x4;
typedef __attribute__((ext_vector_type(8))) short s16x8;

__device__ __forceinline__ float bf2f(ushort u) {
    union { unsigned int i; float f; } v; v.i = ((unsigned int)u) << 16; return v.f;
}
__device__ __forceinline__ ushort f2bf(float f) {
    union { float f; unsigned int u; } v; v.f = f;
    unsigned int u = v.u;
    unsigned int r = (u + 0x7fffu + ((u >> 16) & 1u)) >> 16;
    return (ushort)r;
}

#define GLOAD_LDS16(gptr, lptr) __builtin_amdgcn_global_load_lds( \
    (const __attribute__((address_space(1))) void*)(gptr), \
    (__attribute__((address_space(3))) void*)(lptr), 16, 0, 0)

#define MFMA_BF16(a, b, c) __builtin_amdgcn_mfma_f32_16x16x32_bf16(a, b, c, 0, 0, 0)

// ---------------- embed + nerf positional encoding ----------------
__global__ void embed_kernel(const float* __restrict__ x, const float* __restrict__ W,
                             float* __restrict__ h) {
    int tok = blockIdx.x;
    float xe[3];
#pragma unroll
    for (int e = 0; e < 3; e++) {
        float v = x[tok * 3 + e];
        xe[e] = (v == -100.0f) ? 0.0f : v;
    }
    for (int d = threadIdx.x; d < DM; d += blockDim.x) {
        float pe = 0.0f;
        if (d < 510) {
            int e = d / 170, r = d % 170;
            int is_sin = (r < 85);
            int k = is_sin ? r : r - 85;
            float ang = xe[e] * ldexpf(1.0f, k);   // exact in fp32
            double dv = is_sin ? sin((double)ang) : cos((double)ang);
            pe = (float)dv;
        }
        float acc = pe;
#pragma unroll
        for (int e = 0; e < 3; e++) acc += xe[e] * W[e * DM + d];
        h[(size_t)tok * DM + d] = acc;
    }
}

// ---------------- rmsnorm width=512, wave-per-row (no barriers) -> bf16 --------
__global__ __launch_bounds__(256) void rmsnorm512_bf_kernel(const float* __restrict__ in,
                                                            const float* __restrict__ w,
                                                            ushort* __restrict__ out) {
    int row = blockIdx.x * 4 + (threadIdx.x >> 6);
    int lane = threadIdx.x & 63;
    const float* r = in + (size_t)row * DM + lane * 8;
    f32x4 a = *(const f32x4*)r;
    f32x4 b = *(const f32x4*)(r + 4);
    float ss = a.x*a.x + a.y*a.y + a.z*a.z + a.w*a.w
             + b.x*b.x + b.y*b.y + b.z*b.z + b.w*b.w;
#pragma unroll
    for (int o = 32; o; o >>= 1) ss += __shfl_xor(ss, o);
    float rs = rsqrtf(ss / (float)DM + EPSF);
    const float* wp = w + lane * 8;
    f32x4 w0 = *(const f32x4*)wp;
    f32x4 w1 = *(const f32x4*)(wp + 4);
    s16x8 o8;
    o8[0] = (short)f2bf(a.x * rs * w0.x); o8[1] = (short)f2bf(a.y * rs * w0.y);
    o8[2] = (short)f2bf(a.z * rs * w0.z); o8[3] = (short)f2bf(a.w * rs * w0.w);
    o8[4] = (short)f2bf(b.x * rs * w1.x); o8[5] = (short)f2bf(b.y * rs * w1.y);
    o8[6] = (short)f2bf(b.z * rs * w1.z); o8[7] = (short)f2bf(b.w * rs * w1.w);
    *(s16x8*)(out + (size_t)row * DM + lane * 8) = o8;
}

// ---------------- gate silu(z)*y + rmsnorm width=1024, wave-per-row -> bf16 ------
__global__ __launch_bounds__(256) void gatenorm_kernel(const float* __restrict__ y,
                                                       const ushort* __restrict__ zx,
                                                       const float* __restrict__ gw,
                                                       ushort* __restrict__ yb) {
    int row = blockIdx.x * 4 + (threadIdx.x >> 6);
    int lane = threadIdx.x & 63;
    const float* yp = y + (size_t)row * DI + lane * 16;
    const ushort* zp = zx + (size_t)row * DIP + lane * 16;
    s16x8 z0 = *(const s16x8*)zp;
    s16x8 z1 = *(const s16x8*)(zp + 8);
    float v[16];
    float ss = 0.0f;
#pragma unroll
    for (int e = 0; e < 16; e++) {
        float z = bf2f((ushort)(e < 8 ? z0[e] : z1[e - 8]));
        float s = z / (1.0f + __expf(-z));
        float val = yp[e] * s;
        v[e] = val;
        ss += val * val;
    }
#pragma unroll
    for (int o = 32; o; o >>= 1) ss += __shfl_xor(ss, o);
    float rs = rsqrtf(ss / (float)DI + EPSF);
    const float* gp = gw + lane * 16;
    s16x8 oa, ob;
#pragma unroll
    for (int e = 0; e < 8; e++) {
        oa[e] = (short)f2bf(v[e] * rs * gp[e]);
        ob[e] = (short)f2bf(v[e + 8] * rs * gp[e + 8]);
    }
    ushort* op = yb + (size_t)row * DI + lane * 16;
    *(s16x8*)op = oa;
    *(s16x8*)(op + 8) = ob;
}

// ---------------- weight convert+transpose: w[L][K][N] f32 -> wT[L][Npad][K] bf16 ----
__global__ __launch_bounds__(256) void convT_kernel(const float* __restrict__ w,
                                                    ushort* __restrict__ wT,
                                                    int K, int N, int Npad) {
    __shared__ ushort tile[64][65];
    int l = blockIdx.z;
    int n0 = blockIdx.x * 64, k0 = blockIdx.y * 64;
    const float* src = w + (size_t)l * K * N;
    ushort* dst = wT + (size_t)l * Npad * K;
    int tid = threadIdx.x;
#pragma unroll
    for (int t = 0; t < 16; t++) {
        int idx = tid + t * 256;
        int r = idx >> 6, c = idx & 63;
        float v = (n0 + c < N) ? src[(size_t)(k0 + r) * N + n0 + c] : 0.0f;
        tile[c][r] = f2bf(v);
    }
    __syncthreads();
#pragma unroll
    for (int t = 0; t < 16; t++) {
        int idx = tid + t * 256;
        int r = idx >> 6, c = idx & 63;
        dst[(size_t)(n0 + r) * K + k0 + c] = tile[r][c];
    }
}

// ---------------- bf16 MFMA GEMM: C[M,N] = A[M,K] * BT[N,K]^T ----------------
// BM = MT*32 x BN = NT*32 tile, BK=64, 4 waves (2x2), double-buffered prefetch,
// bijective XCD-aware block swizzle (grid must be %8==0).
// MODE 0: bf16 store + dt sidecar; MODE 1: fp32 accumulate; MODE 2: fp32 + bias (head)
template <int MODE, int MT, int NT>
__global__ __launch_bounds__(256) void gemm_bf16_kernel(
    const ushort* __restrict__ A, const ushort* __restrict__ BT,
    ushort* __restrict__ Cb, float* __restrict__ Cf, float* __restrict__ aux,
    int N, int Nstride, int K)
{
    __shared__ ushort As[2][MT * 32 * 64];
    __shared__ ushort Bs[2][NT * 32 * 64];
    // XCD swizzle: contiguous run of nwg/8 blocks per XCD -> A/B panel L2 reuse
    int nwg = gridDim.x * gridDim.y;
    int w0 = blockIdx.y * gridDim.x + blockIdx.x;
    int wg = (w0 & 7) * (nwg >> 3) + (w0 >> 3);
    int by = wg / gridDim.x, bx = wg - by * gridDim.x;
    int bm = by * (MT * 32), bn = bx * (NT * 32);
    int tid = threadIdx.x;
    int lane = tid & 63, wid = tid >> 6;
    int wr = wid >> 1, wc = wid & 1;
    int r15 = lane & 15, q = lane >> 4;
    f32x4 acc[MT][NT] = {};
    const int nkt = K >> 6;

#define STAGE_GEMM(b, kt) do {                                              \
        int k0s = (kt) << 6;                                                \
        _Pragma("unroll")                                                   \
        for (int t = 0; t < MT; t++) {                                      \
            int cbase = wid * (MT * 64) + t * 64;                           \
            int chunk = cbase + lane;                                       \
            int row = chunk >> 3, s = chunk & 7;                            \
            int kc = s ^ (row & 7);                                         \
            GLOAD_LDS16(A + (size_t)(bm + row) * K + k0s + kc * 8,          \
                        &As[b][cbase * 8]);                                 \
        }                                                                   \
        _Pragma("unroll")                                                   \
        for (int t = 0; t < NT; t++) {                                      \
            int cbase = wid * (NT * 64) + t * 64;                           \
            int chunk = cbase + lane;                                       \
            int row = chunk >> 3, s = chunk & 7;                            \
            int kc = s ^ (row & 7);                                         \
            GLOAD_LDS16(BT + (size_t)(bn + row) * K + k0s + kc * 8,         \
                        &Bs[b][cbase * 8]);                                 \
        }                                                                   \
    } while (0)

    STAGE_GEMM(0, 0);
    __syncthreads();
    for (int kt = 0; kt < nkt; kt++) {
        int cur = kt & 1;
        if (kt + 1 < nkt) STAGE_GEMM(cur ^ 1, kt + 1);
        const ushort* Ac = As[cur];
        const ushort* Bc = Bs[cur];
#pragma unroll
        for (int kh = 0; kh < 2; kh++) {
            s16x8 av[MT], bv[NT];
#pragma unroll
            for (int m = 0; m < MT; m++) {
                int row = wr * (MT * 16) + m * 16 + r15;
                int s = (kh * 4 + q) ^ (row & 7);
                av[m] = *(const s16x8*)(Ac + row * 64 + s * 8);
            }
#pragma unroll
            for (int n = 0; n < NT; n++) {
                int row = wc * (NT * 16) + n * 16 + r15;
                int s = (kh * 4 + q) ^ (row & 7);
                bv[n] = *(const s16x8*)(Bc + row * 64 + s * 8);
            }
#pragma unroll
            for (int m = 0; m < MT; m++)
#pragma unroll
                for (int n = 0; n < NT; n++)
                    acc[m][n] = MFMA_BF16(av[m], bv[n], acc[m][n]);
        }
        __syncthreads();   // drains prefetch (vmcnt0) + guards buffer reuse
    }
#undef STAGE_GEMM

#pragma unroll
    for (int m = 0; m < MT; m++) {
        int row0 = bm + wr * (MT * 16) + m * 16 + q * 4;
#pragma unroll
        for (int n = 0; n < NT; n++) {
            int col = bn + wc * (NT * 16) + n * 16 + r15;
#pragma unroll
            for (int r = 0; r < 4; r++) {
                float v = acc[m][n][r];
                int rr = row0 + r;
                if (MODE == 0) {
                    if (col < N) {
                        Cb[(size_t)rr * Nstride + col] = f2bf(v);
                        if (col >= DI + CONVD) aux[(size_t)rr * 16 + (col - DI - CONVD)] = v;
                    }
                } else if (MODE == 1) {
                    Cf[(size_t)rr * Nstride + col] += v;
                } else {
                    if (col < N) Cf[(size_t)rr * Nstride + col] = v + aux[col];
                }
            }
        }
    }
}

// ---------------- causal depthwise conv (d=4) + bias + silu ------
__global__ __launch_bounds__(256) void conv_kernel(const ushort* __restrict__ zx,
                                                   const float* __restrict__ cw,
                                                   const float* __restrict__ cb,
                                                   ushort* __restrict__ xc) {
    int gid = blockIdx.x * 256 + threadIdx.x;
    int cu = gid % (CONVD / 8);
    int rb = gid / (CONVD / 8);
    int c8 = cu * 8;
    int l0 = rb * 4;
    int lmod = l0 & (SEQL - 1);

    float wk[4][8];
    const float4* wp = (const float4*)(cw + c8 * 4);
#pragma unroll
    for (int e = 0; e < 8; e++) {
        float4 v = wp[e];
        wk[0][e] = v.x; wk[1][e] = v.y; wk[2][e] = v.z; wk[3][e] = v.w;
    }
    float4 b0 = *(const float4*)(cb + c8);
    float4 b1 = *(const float4*)(cb + c8 + 4);
    float bias[8] = {b0.x, b0.y, b0.z, b0.w, b1.x, b1.y, b1.z, b1.w};

    const ushort* base = zx + (size_t)l0 * DIP + DI + c8;
    s16x8 zero = {};
    s16x8 rows[7];
    rows[0] = (lmod >= 3) ? *(const s16x8*)(base - 3 * DIP) : zero;
    rows[1] = (lmod >= 2) ? *(const s16x8*)(base - 2 * DIP) : zero;
    rows[2] = (lmod >= 1) ? *(const s16x8*)(base - 1 * DIP) : zero;
#pragma unroll
    for (int r = 0; r < 4; r++) rows[3 + r] = *(const s16x8*)(base + (size_t)r * DIP);

    ushort* ob = xc + (size_t)l0 * CONVD + c8;
#pragma unroll
    for (int r = 0; r < 4; r++) {
        s16x8 o;
#pragma unroll
        for (int e = 0; e < 8; e++) {
            float a = bias[e];
#pragma unroll
            for (int k = 0; k < 4; k++)
                a += bf2f((ushort)rows[r + k][e]) * wk[k][e];
            float s = a / (1.0f + __expf(-a));
            o[e] = (short)f2bf(s);
        }
        *(s16x8*)(ob + (size_t)r * CONVD) = o;
    }
}

// ---------------- F1: fused dt-scan + scores + M + y_diag(+D via M-diag) + state ----
// grid (NH, 32 bc); 512 threads (8 waves).
__global__ __launch_bounds__(512, 4) void ssd1_kernel(
    const ushort* __restrict__ xc, const float* __restrict__ dtraw,
    const float* __restrict__ dt_bias, const float* __restrict__ A_log,
    const float* __restrict__ Dp, float* __restrict__ acg,
    float* __restrict__ decbuf, float* __restrict__ y, float* __restrict__ S)
{
    __shared__ ushort Mb[128 * 128];
    __shared__ ushort xhT[64 * 136];
    __shared__ ushort BmT[64 * 136];
    __shared__ float sAc[128], sDt[128], sDs[128];
    __shared__ float s_wsum, s_stot;

    int hh = blockIdx.x, bc = blockIdx.y;
    int tid = threadIdx.x, lane = tid & 63, w = tid >> 6;
    int l15 = lane & 15, lq = lane >> 4;
    int bch = bc * NH + hh;
    const size_t xbase = (size_t)(bc * CHK) * CONVD;
    ushort* Cs = Mb;
    ushort* Bs = Mb + 8192;
    float Dh = Dp[hh];

#pragma unroll
    for (int t = 0; t < 2; t++) {
        int cbase = t * 512 + w * 64;
        int chunk = cbase + lane;
        int row = chunk >> 3, s = chunk & 7;
        int kc = s ^ (row & 7);
        GLOAD_LDS16(xc + xbase + (size_t)row * CONVD + DI + DSTATE + kc * 8, Cs + (size_t)cbase * 8);
        GLOAD_LDS16(xc + xbase + (size_t)row * CONVD + DI + kc * 8, Bs + (size_t)cbase * 8);
    }
    {
        int j = tid & 127, pc = tid >> 7;
#pragma unroll
        for (int it = 0; it < 2; it++) {
            int pc8 = pc * 2 + it;
            s16x8 vx = *(const s16x8*)(xc + xbase + (size_t)j * CONVD + hh * HD + pc8 * 8);
            s16x8 vb = *(const s16x8*)(xc + xbase + (size_t)j * CONVD + DI + pc8 * 8);
#pragma unroll
            for (int e = 0; e < 8; e++) {
                int R = pc8 * 8 + e;
                int off = R * 136 + (((j >> 3) ^ (R & 7)) << 3) + (j & 7);
                xhT[off] = (ushort)vx[e];
                BmT[off] = (ushort)vb[e];
            }
        }
    }
    float v_scan = 0.0f, dt_v = 0.0f;
    if (tid < 128) {
        float raw = dtraw[(size_t)(bc * CHK + tid) * 16 + hh] + dt_bias[hh];
        dt_v = raw > 0.0f ? raw + log1pf(__expf(-raw)) : log1pf(__expf(raw));
        v_scan = dt_v * (-__expf(A_log[hh]));
#pragma unroll
        for (int o = 1; o < 64; o <<= 1) {
            float u = __shfl_up(v_scan, o);
            if (lane >= o) v_scan += u;
        }
        if (tid == 63) s_wsum = v_scan;
    }
    __syncthreads();   // B1

    float ac_v = 0.0f;
    if (tid < 128) {
        ac_v = (tid >= 64) ? v_scan + s_wsum : v_scan;
        if (tid == 127) s_stot = ac_v;
    }
    f32x4 acc_s[8] = {};
    {
        int row = w * 16 + l15;
#pragma unroll
        for (int kh = 0; kh < 2; kh++) {
            int sl = (kh * 4 + lq) ^ (row & 7);
            s16x8 av = *(const s16x8*)(Cs + row * 64 + sl * 8);
#pragma unroll
            for (int nj = 0; nj < 8; nj++) {
                int jr = nj * 16 + l15;
                int sl2 = (kh * 4 + lq) ^ (jr & 7);
                s16x8 bv = *(const s16x8*)(Bs + jr * 64 + sl2 * 8);
                acc_s[nj] = MFMA_BF16(av, bv, acc_s[nj]);
            }
        }
    }
    __syncthreads();   // B2

    if (tid < 128) {
        float asum = s_stot;
        sAc[tid] = ac_v;
        sDt[tid] = dt_v;
        sDs[tid] = __expf(asum - ac_v) * dt_v;
        acg[(size_t)bch * CHK + tid] = ac_v;
        if (tid == 0) decbuf[bch] = __expf(asum);
    }
    __syncthreads();   // B3

    // M-build (D folded into diagonal)
#pragma unroll
    for (int nj = 0; nj < 8; nj++) {
        int j = nj * 16 + l15;
        if (nj < w) {
            float acj = sAc[j], dtj = sDt[j];
#pragma unroll
            for (int r = 0; r < 4; r++) {
                int i = w * 16 + lq * 4 + r;
                float v = acc_s[nj][r] * __expf(sAc[i] - acj) * dtj;
                Mb[i * 128 + ((((i & 7) ^ (j >> 3)) << 3) | (j & 7))] = f2bf(v);
            }
        } else if (nj == w) {
            float acj = sAc[j], dtj = sDt[j];
#pragma unroll
            for (int r = 0; r < 4; r++) {
                int i = w * 16 + lq * 4 + r;
                float v;
                if (j < i)       v = acc_s[nj][r] * __expf(sAc[i] - acj) * dtj;
                else if (j == i) v = acc_s[nj][r] * dtj + Dh;
                else             v = 0.0f;
                Mb[i * 128 + ((((i & 7) ^ (j >> 3)) << 3) | (j & 7))] = f2bf(v);
            }
        } else if (nj == w + 1) {
#pragma unroll
            for (int r = 0; r < 4; r++) {
                int i = w * 16 + lq * 4 + r;
                Mb[i * 128 + ((((i & 7) ^ (j >> 3)) << 3) | (j & 7))] = 0;
            }
        }
    }
    // BmT *= ds_j (in place; read only after B4)
    {
        int j = tid & 127, g = tid >> 7;
        float dsj = sDs[j];
#pragma unroll
        for (int rr = 0; rr < 16; rr++) {
            int R = g * 16 + rr;
            int off = R * 136 + (((j >> 3) ^ (R & 7)) << 3) + (j & 7);
            BmT[off] = f2bf(bf2f(BmT[off]) * dsj);
        }
    }
    __syncthreads();   // B4

    int ph = w >> 2, iq = w & 3;
    f32x4 acc_y[2][2] = {};
    f32x4 acc_st[2] = {};
    int nn = iq * 16 + l15;
#pragma unroll
    for (int ks = 0; ks < 4; ks++) {
        int cj = ks * 4 + lq;
        s16x8 axh[2];
#pragma unroll
        for (int m = 0; m < 2; m++) {
            int p = ph * 32 + m * 16 + l15;
            axh[m] = *(const s16x8*)(xhT + p * 136 + ((cj ^ (p & 7)) << 3));
        }
        s16x8 bb = *(const s16x8*)(BmT + nn * 136 + ((cj ^ (nn & 7)) << 3));
#pragma unroll
        for (int m = 0; m < 2; m++)
            acc_st[m] = MFMA_BF16(axh[m], bb, acc_st[m]);
        if (ks <= iq) {
            s16x8 bm_[2];
#pragma unroll
            for (int n = 0; n < 2; n++) {
                int i = iq * 32 + n * 16 + l15;
                bm_[n] = *(const s16x8*)(Mb + i * 128 + ((cj ^ (i & 7)) << 3));
            }
#pragma unroll
            for (int m = 0; m < 2; m++)
#pragma unroll
                for (int n = 0; n < 2; n++)
                    acc_y[m][n] = MFMA_BF16(axh[m], bm_[n], acc_y[m][n]);
        }
    }

#pragma unroll
    for (int m = 0; m < 2; m++) {
        int p0 = ph * 32 + m * 16 + lq * 4;
#pragma unroll
        for (int n = 0; n < 2; n++) {
            int i = iq * 32 + n * 16 + l15;
            *(f32x4*)&y[(size_t)(bc * CHK + i) * DI + hh * HD + p0] = acc_y[m][n];
        }
#pragma unroll
        for (int r = 0; r < 4; r++)
            S[(size_t)bch * 4096 + (size_t)(p0 + r) * 64 + nn] = acc_st[m][r];
    }
}

// ---------------- F2: y += exp(ac_i) * (C @ hs^T); hs computed in-block ------
__global__ __launch_bounds__(256) void ssd2_kernel(
    const ushort* __restrict__ xc, const float* __restrict__ Sg,
    const float* __restrict__ decg, const float* __restrict__ acg,
    float* __restrict__ y)
{
    __shared__ ushort Cs[128 * 64];
    __shared__ ushort Hs[64 * 64];
    __shared__ float sAc[128];
    int hh = blockIdx.x, bc = blockIdx.y;
    int tid = threadIdx.x, lane = tid & 63, wid = tid >> 6;
    int wr = wid >> 1, wc = wid & 1, l15 = lane & 15, lq = lane >> 4;
    int bch = bc * NH + hh;
    int b = bc >> 4, cc = bc & 15;
    const size_t xbase = (size_t)(bc * CHK) * CONVD;
#pragma unroll
    for (int t = 0; t < 4; t++) {
        int cbase = t * 256 + wid * 64;
        int chunk = cbase + lane;
        int row = chunk >> 3, s = chunk & 7;
        int kc = s ^ (row & 7);
        GLOAD_LDS16(xc + xbase + (size_t)row * CONVD + DI + DSTATE + kc * 8, Cs + (size_t)cbase * 8);
    }
    {
        int p = tid >> 2, n0 = (tid & 3) * 16;
        f32x4 acc4[4] = {};
        float wgt = 1.0f;
        for (int c = cc - 1; c >= 0; --c) {
            int bch_c = (b * NCH + c) * NH + hh;
            const float* src = Sg + (size_t)bch_c * 4096 + p * 64 + n0;
            float dv = decg[bch_c];
#pragma unroll
            for (int q2 = 0; q2 < 4; q2++) {
                f32x4 sv = *(const f32x4*)(src + q2 * 4);
                acc4[q2].x += sv.x * wgt; acc4[q2].y += sv.y * wgt;
                acc4[q2].z += sv.z * wgt; acc4[q2].w += sv.w * wgt;
            }
            wgt *= dv;
        }
#pragma unroll
        for (int g = 0; g < 2; g++) {
            int nch = (n0 >> 3) + g;
            int s = nch ^ (p & 7);
            ushort* dst = Hs + p * 64 + s * 8;
#pragma unroll
            for (int ee = 0; ee < 8; ee++) {
                int idx = g * 8 + ee;
                dst[ee] = f2bf(acc4[idx >> 2][idx & 3]);
            }
        }
    }
    if (tid < 128) sAc[tid] = acg[(size_t)bch * CHK + tid];
    __syncthreads();
    f32x4 acc[2][4] = {};
#pragma unroll
    for (int kh = 0; kh < 2; kh++) {
        s16x8 av[2], bv[4];
#pragma unroll
        for (int m = 0; m < 2; m++) {
            int p = wr * 32 + m * 16 + l15;
            int sl = (kh * 4 + lq) ^ (p & 7);
            av[m] = *(const s16x8*)(Hs + p * 64 + sl * 8);
        }
#pragma unroll
        for (int n = 0; n < 4; n++) {
            int i = wc * 64 + n * 16 + l15;
            int sl = (kh * 4 + lq) ^ (i & 7);
            bv[n] = *(const s16x8*)(Cs + i * 64 + sl * 8);
        }
#pragma unroll
        for (int m = 0; m < 2; m++)
#pragma unroll
            for (int n = 0; n < 4; n++)
                acc[m][n] = MFMA_BF16(av[m], bv[n], acc[m][n]);
    }
#pragma unroll
    for (int m = 0; m < 2; m++) {
        int p0 = wr * 32 + m * 16 + lq * 4;
#pragma unroll
        for (int n = 0; n < 4; n++) {
            int i = wc * 64 + n * 16 + l15;
            float e = __expf(sAc[i]);
            float* dst = &y[(size_t)(bc * CHK + i) * DI + hh * HD + p0];
            f32x4 v = *(f32x4*)dst;
#pragma unroll
            for (int r = 0; r < 4; r++) v[r] += e * acc[m][n][r];
            *(f32x4*)dst = v;
        }
    }
}

extern "C" void kernel_launch(void* const* d_in, const int* in_sizes, int n_in,
                              void* d_out, int out_size, void* d_ws, size_t ws_size,
                              hipStream_t stream) {
    const float* x        = (const float*)d_in[0];
    const float* W_embed  = (const float*)d_in[1];
    const float* rms_w    = (const float*)d_in[2];
    const float* in_w     = (const float*)d_in[3];
    const float* conv_w   = (const float*)d_in[4];
    const float* conv_b   = (const float*)d_in[5];
    const float* dt_bias  = (const float*)d_in[6];
    const float* A_log    = (const float*)d_in[7];
    const float* D_param  = (const float*)d_in[8];
    const float* gnorm_w  = (const float*)d_in[9];
    const float* out_w    = (const float*)d_in[10];
    const float* fnorm_w  = (const float*)d_in[11];
    const float* head_w   = (const float*)d_in[12];
    const float* head_b   = (const float*)d_in[13];
    float* out = (float*)d_out;

    char* p = (char*)d_ws;
    auto alloc = [&](size_t bytes) { char* r = p; p += (bytes + 255) & ~(size_t)255; return r; };

    float*  h_buf   = (float*)alloc((size_t)BL * DM * 4);
    float*  y_buf   = (float*)alloc((size_t)BL * DI * 4);
    float*  S_buf   = (float*)alloc((size_t)BSZ * NCH * NH * HD * DSTATE * 4);
    float*  ac_buf  = (float*)alloc((size_t)BSZ * NCH * NH * CHK * 4);
    float*  dec_buf = (float*)alloc((size_t)BSZ * NCH * NH * 4);
    float*  dtraw   = (float*)alloc((size_t)BL * 16 * 4);
    ushort* xn_bf   = (ushort*)alloc((size_t)BL * DM * 2);
    ushort* zx_bf   = (ushort*)alloc((size_t)BL * DIP * 2);
    ushort* xc_bf   = (ushort*)alloc((size_t)BL * CONVD * 2);
    ushort* y_bf    = (ushort*)alloc((size_t)BL * DI * 2);
    ushort* headT   = (ushort*)alloc((size_t)128 * DM * 2);

    size_t in_full  = (size_t)NLAYER * NPAD_IN * DM * 2;
    size_t out_full = (size_t)NLAYER * DM * DI * 2;
    size_t used = (size_t)(p - (char*)d_ws);
    bool full = (used + in_full + out_full + 4096) <= ws_size;
    ushort* inT  = (ushort*)alloc(full ? in_full  : (size_t)NPAD_IN * DM * 2);
    ushort* outT = (ushort*)alloc(full ? out_full : (size_t)DM * DI * 2);

    embed_kernel<<<BL, 256, 0, stream>>>(x, W_embed, h_buf);
    convT_kernel<<<dim3(2, DM / 64, 1), 256, 0, stream>>>(head_w, headT, DM, 30, 128);
    if (full) {
        convT_kernel<<<dim3(NPAD_IN / 64, DM / 64, NLAYER), 256, 0, stream>>>(
            in_w, inT, DM, DIP, NPAD_IN);
        convT_kernel<<<dim3(DM / 64, DI / 64, NLAYER), 256, 0, stream>>>(
            out_w, outT, DI, DM, DM);
    }

    for (int l = 0; l < NLAYER; l++) {
        const float* rw = rms_w + (size_t)l * DM;
        const float* cw = conv_w + (size_t)l * CONVD * 4;
        const float* cb = conv_b + (size_t)l * CONVD;
        const float* db = dt_bias + (size_t)l * NH;
        const float* al = A_log + (size_t)l * NH;
        const float* dp = D_param + (size_t)l * NH;
        const float* gw = gnorm_w + (size_t)l * DI;

        ushort* inT_l  = full ? inT  + (size_t)l * NPAD_IN * DM : inT;
        ushort* outT_l = full ? outT + (size_t)l * DM * DI      : outT;
        if (!full) {
            convT_kernel<<<dim3(NPAD_IN / 64, DM / 64, 1), 256, 0, stream>>>(
                in_w + (size_t)l * DM * DIP, inT_l, DM, DIP, NPAD_IN);
            convT_kernel<<<dim3(DM / 64, DI / 64, 1), 256, 0, stream>>>(
                out_w + (size_t)l * DI * DM, outT_l, DI, DM, DM);
        }

        rmsnorm512_bf_kernel<<<BL / 4, 256, 0, stream>>>(h_buf, rw, xn_bf);
        gemm_bf16_kernel<0, 1, 4><<<dim3(NPAD_IN / 128, BL / 32), 256, 0, stream>>>(
            xn_bf, inT_l, zx_bf, nullptr, dtraw, DIP, DIP, DM);
        conv_kernel<<<((BL / 4) * (CONVD / 8)) / 256, 256, 0, stream>>>(zx_bf, cw, cb, xc_bf);
        ssd1_kernel<<<dim3(NH, BSZ * NCH), 512, 0, stream>>>(xc_bf, dtraw, db, al, dp,
                                                             ac_buf, dec_buf, y_buf, S_buf);
        ssd2_kernel<<<dim3(NH, BSZ * NCH), 256, 0, stream>>>(xc_bf, S_buf, dec_buf,
                                                             ac_buf, y_buf);
        gatenorm_kernel<<<BL / 4, 256, 0, stream>>>(y_buf, zx_bf, gw, y_bf);
        gemm_bf16_kernel<1, 1, 2><<<dim3(DM / 64, BL / 32), 256, 0, stream>>>(
            y_bf, outT_l, nullptr, h_buf, nullptr, DM, DM, DI);
    }

    rmsnorm512_bf_kernel<<<BL / 4, 256, 0, stream>>>(h_buf, fnorm_w, xn_bf);
    gemm_bf16_kernel<2, 4, 1><<<dim3(1, BL / 128), 256, 0, stream>>>(
        xn_bf, headT, nullptr, out, (float*)head_b, 30, 30, DM);
}